// Round 6
// baseline (204.793 us; speedup 1.0000x reference)
//
#include <hip/hip_runtime.h>
#include <hip/hip_bf16.h>
#include <stdint.h>

// Problem constants
#define HID 1024
#define SEQ 2048
#define BATCH 2
#define NHEADS 16
#define HEADDIM 64
#define MROWS (BATCH*SEQ)   // 4096

#define GAS __attribute__((address_space(1)))
#define LAS __attribute__((address_space(3)))

typedef __attribute__((ext_vector_type(8))) __bf16 bf16x8;
typedef __attribute__((ext_vector_type(4))) float f32x4;
typedef __attribute__((ext_vector_type(16))) float f32x16;

__device__ __forceinline__ ushort f2bf(float f) {
  union { float f; uint32_t u; } v; v.f = f;
  return (ushort)((v.u + 0x7FFFu + ((v.u >> 16) & 1u)) >> 16);
}

__device__ __forceinline__ void gl_lds16(const void* g, void* l) {
  __builtin_amdgcn_global_load_lds((const GAS void*)g, (LAS void*)l, 16, 0, 0);
}

// pack 2 f32 -> 2 bf16 in one u32 (lo = a, hi = b), RNE
__device__ __forceinline__ uint32_t cvtpk(float a, float b) {
  uint32_t r;
  asm("v_cvt_pk_bf16_f32 %0, %1, %2" : "=v"(r) : "v"(a), "v"(b));
  return r;
}

// swap: a_hi <-> b_lo  =>  a' = [a_lo, b_lo], b' = [a_hi, b_hi]
__device__ __forceinline__ void pl32swap(uint32_t& a, uint32_t& b) {
  asm("v_permlane32_swap_b32 %0, %1" : "+v"(a), "+v"(b));
}

// ---------------- weight fp32 -> bf16 convert ----------------
__global__ __launch_bounds__(256) void k_cvt(const float* __restrict__ Wq,
                                             const float* __restrict__ Wk,
                                             const float* __restrict__ Wv,
                                             const float* __restrict__ Wo,
                                             ushort* __restrict__ dst) {
  int mat = blockIdx.y;
  const float* src = (mat == 0) ? Wq : (mat == 1) ? Wk : (mat == 2) ? Wv : Wo;
  int off = (blockIdx.x * 256 + threadIdx.x) * 4;
  float4 v = *(const float4*)(src + off);
  ushort4 o;
  o.x = f2bf(v.x); o.y = f2bf(v.y); o.z = f2bf(v.z); o.w = f2bf(v.w);
  *(ushort4*)(dst + (size_t)mat * (HID * HID) + off) = o;
}

// ---------------- LayerNorm fp32 -> bf16 ----------------
__global__ __launch_bounds__(256) void k_ln(const float* __restrict__ x,
                                            const float* __restrict__ g,
                                            const float* __restrict__ b,
                                            ushort* __restrict__ xn) {
  int row = blockIdx.x;
  int t = threadIdx.x;
  const float* xr = x + (size_t)row * HID;
  float4 v = *(const float4*)(xr + t * 4);
  float s = v.x + v.y + v.z + v.w;
  float s2 = v.x * v.x + v.y * v.y + v.z * v.z + v.w * v.w;
  for (int m = 1; m < 64; m <<= 1) { s += __shfl_xor(s, m); s2 += __shfl_xor(s2, m); }
  __shared__ float ws[4], ws2[4];
  int wid = t >> 6;
  if ((t & 63) == 0) { ws[wid] = s; ws2[wid] = s2; }
  __syncthreads();
  s = ws[0] + ws[1] + ws[2] + ws[3];
  s2 = ws2[0] + ws2[1] + ws2[2] + ws2[3];
  float mu = s * (1.0f / HID);
  float var = s2 * (1.0f / HID) - mu * mu;
  float rstd = rsqrtf(var + 1e-5f);
  float4 gg = *(const float4*)(g + t * 4);
  float4 bb = *(const float4*)(b + t * 4);
  ushort4 o;
  o.x = f2bf((v.x - mu) * rstd * gg.x + bb.x);
  o.y = f2bf((v.y - mu) * rstd * gg.y + bb.y);
  o.z = f2bf((v.z - mu) * rstd * gg.z + bb.z);
  o.w = f2bf((v.w - mu) * rstd * gg.w + bb.w);
  *(ushort4*)(xn + (size_t)row * HID + t * 4) = o;
}

// ---------------- fused QKV GEMM ----------------
// Q pre-scaled by 0.125*log2(e). V written TRANSPOSED: [bh][d][s].
__global__ __launch_bounds__(256) void k_qkv(const ushort* __restrict__ xn,
                                             const ushort* __restrict__ wmat,
                                             const float* __restrict__ bq,
                                             const float* __restrict__ bk,
                                             const float* __restrict__ bv,
                                             ushort* __restrict__ qo,
                                             ushort* __restrict__ ko,
                                             ushort* __restrict__ vo) {
  __shared__ ushort As[128 * 32];
  __shared__ ushort Bs[128 * 32];
  int tid = threadIdx.x;
  int lane = tid & 63;
  int wv = tid >> 6;
  int quad = lane >> 4;
  int l16 = lane & 15;
  int m0 = blockIdx.x * 128;
  int ng = blockIdx.y * 128;
  int mat = ng >> 10;            // 0,1,2
  int nloc = ng & 1023;
  const ushort* wptr = wmat + (size_t)mat * (HID * HID) + (size_t)nloc * HID;
  const float* bias = (mat == 0) ? bq : (mat == 1) ? bk : bv;
  ushort* outp = (mat == 0) ? qo : (mat == 1) ? ko : vo;
  const float scl = (mat == 0) ? 0.18033688011112042f : 1.0f;

  int arow = tid >> 2;
  int acol = (tid & 3) * 8;
  int wm = (wv >> 1) * 64, wn = (wv & 1) * 64;

  f32x4 acc[4][4] = {};
  for (int k0 = 0; k0 < HID; k0 += 32) {
    __syncthreads();
    for (int t = 0; t < 2; t++) {
      gl_lds16(xn + (size_t)(m0 + t * 64 + arow) * HID + k0 + acol,
               As + t * 2048 + wv * 512);
      gl_lds16(wptr + (size_t)(t * 64 + arow) * HID + k0 + acol,
               Bs + t * 2048 + wv * 512);
    }
    __syncthreads();
    bf16x8 af[4], bfr[4];
    for (int i = 0; i < 4; i++)
      af[i] = *(const bf16x8*)&As[(wm + i * 16 + l16) * 32 + quad * 8];
    for (int n = 0; n < 4; n++)
      bfr[n] = *(const bf16x8*)&Bs[(wn + n * 16 + l16) * 32 + quad * 8];
    for (int i = 0; i < 4; i++)
      for (int n = 0; n < 4; n++)
        acc[i][n] = __builtin_amdgcn_mfma_f32_16x16x32_bf16(af[i], bfr[n], acc[i][n], 0, 0, 0);
  }
  float bv4[4];
  for (int n = 0; n < 4; n++) bv4[n] = bias[nloc + wn + n * 16 + l16];
  for (int i = 0; i < 4; i++) {
    int mrow = m0 + wm + i * 16 + quad * 4;
    for (int n = 0; n < 4; n++) {
      int col = nloc + wn + n * 16 + l16;
      int h = col >> 6, d = col & 63;
      for (int r = 0; r < 4; r++) {
        int m = mrow + r;
        int bidx = m >> 11, sidx = m & 2047;
        size_t dst;
        if (mat == 2)  // V transposed: [bh][d][s]
          dst = (((size_t)(bidx * NHEADS + h) * HEADDIM) + d) * SEQ + sidx;
        else
          dst = (((size_t)(bidx * NHEADS + h) * SEQ) + sidx) * HEADDIM + d;
        outp[dst] = f2bf((acc[i][n][r] + bv4[n]) * scl);
      }
    }
  }
}

// ---------------- flash attention v7: key-split waves (halve per-wave LDS reads) ----
// v6 analysis: wall 1944 cyc/body; per-CU LDS read demand 8 waves x 16KB =
// 128KB/body = ~1540-1660 cyc at 85-107 B/cyc -> LDS-BW-BOUND. Cause: all 4
// waves each read the ENTIRE K+V tile (4x cross-wave redundancy).
// v7: wave (wq,wk) = (wv&1, wv>>1) handles q-rows [wq*64,+64) x keys
// [wk*32,+32) of each tile -> per-wave reads: 4 K + 4 V b128 = 8KB (half).
// MFMA count unchanged (8 QK + 8 PV + 4 Os). Softmax cvtpk/permlane machinery
// byte-identical (operates per 32-key C-tile; key-group base shifts by wk*32
// consistently in both P and V granules). O/Os now PARTIAL over keys ->
// one cross-wave (wk=1 -> wk=0) LDS reduction in the epilogue (48KB, once).
// Pipeline skeleton (depth-2 DMA, counted vmcnt(4), raw s_barrier) = v6.
#define E2(x) __builtin_amdgcn_exp2f(x)
#define MFMA(a, b, c) __builtin_amdgcn_mfma_f32_32x32x16_bf16(a, b, c, 0, 0, 0)

#define SOFTMAX_PF(S0, S1)                                                     \
    union { uint32_t u[4]; bf16x8 v; } pf0, pf1, pf2, pf3;                     \
    {                                                                          \
      uint32_t c0 = cvtpk(E2(S0[0]),  E2(S0[1]));                              \
      uint32_t c1 = cvtpk(E2(S0[2]),  E2(S0[3]));                              \
      uint32_t c2 = cvtpk(E2(S0[4]),  E2(S0[5]));                              \
      uint32_t c3 = cvtpk(E2(S0[6]),  E2(S0[7]));                              \
      uint32_t c4 = cvtpk(E2(S0[8]),  E2(S0[9]));                              \
      uint32_t c5 = cvtpk(E2(S0[10]), E2(S0[11]));                             \
      uint32_t c6 = cvtpk(E2(S0[12]), E2(S0[13]));                             \
      uint32_t c7 = cvtpk(E2(S0[14]), E2(S0[15]));                             \
      pl32swap(c0, c2); pl32swap(c1, c3); pl32swap(c4, c6); pl32swap(c5, c7);  \
      pf0.u[0] = c0; pf0.u[1] = c1; pf0.u[2] = c2; pf0.u[3] = c3;              \
      pf1.u[0] = c4; pf1.u[1] = c5; pf1.u[2] = c6; pf1.u[3] = c7;              \
    }                                                                          \
    {                                                                          \
      uint32_t c0 = cvtpk(E2(S1[0]),  E2(S1[1]));                              \
      uint32_t c1 = cvtpk(E2(S1[2]),  E2(S1[3]));                              \
      uint32_t c2 = cvtpk(E2(S1[4]),  E2(S1[5]));                              \
      uint32_t c3 = cvtpk(E2(S1[6]),  E2(S1[7]));                              \
      uint32_t c4 = cvtpk(E2(S1[8]),  E2(S1[9]));                              \
      uint32_t c5 = cvtpk(E2(S1[10]), E2(S1[11]));                             \
      uint32_t c6 = cvtpk(E2(S1[12]), E2(S1[13]));                             \
      uint32_t c7 = cvtpk(E2(S1[14]), E2(S1[15]));                             \
      pl32swap(c0, c2); pl32swap(c1, c3); pl32swap(c4, c6); pl32swap(c5, c7);  \
      pf2.u[0] = c0; pf2.u[1] = c1; pf2.u[2] = c2; pf2.u[3] = c3;              \
      pf3.u[0] = c4; pf3.u[1] = c5; pf3.u[2] = c6; pf3.u[3] = c7;              \
    }

// softmax(SP0,SP1) + PV from VSM(VS). pf0/pf1 = (qg0, kf0/1); pf2/pf3 = (qg1).
// vf{kf}{dg} granule = wk*4 + 2*kf + hi, row = dg*32 + l32.
#define PV_STEP(VS, SP0, SP1)                                                  \
    bf16x8 vf00 = *(const bf16x8*)&VSM(VS)[l32 * 64 + (((wk4 + hi) ^ rsw) * 8)];           \
    bf16x8 vf10 = *(const bf16x8*)&VSM(VS)[l32 * 64 + (((wk4 + 2 + hi) ^ rsw) * 8)];       \
    bf16x8 vf01 = *(const bf16x8*)&VSM(VS)[(32 + l32) * 64 + (((wk4 + hi) ^ rsw) * 8)];    \
    bf16x8 vf11 = *(const bf16x8*)&VSM(VS)[(32 + l32) * 64 + (((wk4 + 2 + hi) ^ rsw) * 8)];\
    SOFTMAX_PF(SP0, SP1)                                                       \
    __builtin_amdgcn_s_setprio(1);                                             \
    Oa00 = MFMA(pf0.v, vf00, Oa00); Oa00 = MFMA(pf1.v, vf10, Oa00);            \
    Oa01 = MFMA(pf0.v, vf01, Oa01); Oa01 = MFMA(pf1.v, vf11, Oa01);            \
    Oa10 = MFMA(pf2.v, vf00, Oa10); Oa10 = MFMA(pf3.v, vf10, Oa10);            \
    Oa11 = MFMA(pf2.v, vf01, Oa11); Oa11 = MFMA(pf3.v, vf11, Oa11);            \
    Os0  = MFMA(pf0.v, ones, Os0);  Os0  = MFMA(pf1.v, ones, Os0);             \
    Os1  = MFMA(pf2.v, ones, Os1);  Os1  = MFMA(pf3.v, ones, Os1);             \
    __builtin_amdgcn_s_setprio(0);

// Body t: DMA tile t+2, QK(t)->SC (keys wk*32..+32), softmax+PV(t-1),
// counted s_waitcnt + raw s_barrier (v6 scheme).
#define ATTN_BODY(T, SC0, SC1, SP0, SP1, DO_DMA, WAITN)                        \
  do {                                                                         \
    if (DO_DMA) {                                                              \
      size_t ko = (size_t)((T) + 2) * 64 * HEADDIM;                            \
      size_t vo = (size_t)((T) + 2) * 64;                                      \
      gl_lds16(kSrcA + ko, KSM(kd) + ldsA);                                    \
      gl_lds16(kSrcB + ko, KSM(kd) + ldsB);                                    \
      gl_lds16(vSrcA + vo, VSM(vd) + ldsA);                                    \
      gl_lds16(vSrcB + vo, VSM(vd) + ldsB);                                    \
    }                                                                          \
    SC0 = (f32x16){}; SC1 = (f32x16){};                                        \
    __builtin_amdgcn_s_setprio(1);                                             \
    _Pragma("unroll")                                                          \
    for (int f = 0; f < 4; f++) {                                              \
      bf16x8 kfr = *(const bf16x8*)&KSM(kr)[(wk32 + l32) * 64 +                \
                                            (((2 * f + hi) ^ rsw) * 8)];       \
      SC0 = MFMA(kfr, qf0[f], SC0);                                            \
      SC1 = MFMA(kfr, qf1[f], SC1);                                            \
    }                                                                          \
    __builtin_amdgcn_s_setprio(0);                                             \
    PV_STEP(vr, SP0, SP1)                                                      \
    asm volatile("s_waitcnt vmcnt(" #WAITN ")" ::: "memory");                  \
    __builtin_amdgcn_s_barrier();                                              \
    __builtin_amdgcn_sched_barrier(0);                                         \
    kr = (kr == 2) ? 0 : kr + 1;  kd = (kd == 2) ? 0 : kd + 1;                 \
    vr = (vr + 1) & 3;  vd = (vd + 1) & 3;                                     \
  } while (0)

__global__ __launch_bounds__(256, 2) void k_attn(const ushort* __restrict__ Q,
                                                 const ushort* __restrict__ K,
                                                 const ushort* __restrict__ Vt,
                                                 ushort* __restrict__ ctx) {
  // arena: K[3] (24KB) + V[4] (32KB) = 56KB; reused as 48KB f32 reduction buf.
  __shared__ __align__(16) unsigned char arena[57344];
#define KSM(i) ((ushort*)arena + (i) * 4096)
#define VSM(i) ((ushort*)(arena + 24576) + (i) * 4096)
  int tid = threadIdx.x, lane = tid & 63, wv = tid >> 6;
  int l32 = lane & 31, hi = lane >> 5;
  int wq = wv & 1, wk = wv >> 1;
  int wk32 = wk * 32, wk4 = wk * 4;
  int bh = blockIdx.x;                 // XCD-grouped: id%8 == bh%8 (v5)
  int q0 = blockIdx.y * 128;
  const ushort* Qb = Q + ((size_t)bh * SEQ + q0 + wq * 64 + l32) * HEADDIM;
  const ushort* Kb = K + (size_t)bh * SEQ * HEADDIM;
  const ushort* Vb = Vt + (size_t)bh * HEADDIM * SEQ;   // [d][s]

  // Q as B-frags, 2 q-groups of 32: col=l32, k(d) = f*16 + hi*8 + j.
  bf16x8 qf0[4], qf1[4];
#pragma unroll
  for (int f = 0; f < 4; f++) {
    qf0[f] = *(const bf16x8*)(Qb + f * 16 + hi * 8);
    qf1[f] = *(const bf16x8*)(Qb + 32 * HEADDIM + f * 16 + hi * 8);
  }

  bf16x8 ones;
#pragma unroll
  for (int j = 0; j < 8; j++) ones[j] = (__bf16)1.0f;

  // staging source addresses (pre-swizzled): LDS dest row = wv*8+(lane>>3),
  // slot = lane&7; logical granule g lands at slot g^(row&7).
  int gsl = lane & 7;
  int rowA = wv * 8 + (lane >> 3);        // rows 0..31
  int rowB = 32 + wv * 8 + (lane >> 3);   // rows 32..63
  const ushort* kSrcA = Kb + rowA * HEADDIM + ((gsl ^ (rowA & 7)) * 8);
  const ushort* kSrcB = Kb + rowB * HEADDIM + ((gsl ^ (rowB & 7)) * 8);
  const ushort* vSrcA = Vb + (size_t)rowA * SEQ + ((gsl ^ (rowA & 7)) * 8);
  const ushort* vSrcB = Vb + (size_t)rowB * SEQ + ((gsl ^ (rowB & 7)) * 8);
  int ldsA = wv * 512;          // ushort idx (1 KB per wave-issue)
  int ldsB = 2048 + wv * 512;

  f32x16 Oa00 = {}, Oa01 = {}, Oa10 = {}, Oa11 = {}, Os0 = {}, Os1 = {};
  f32x16 sA0, sA1, sB0, sB1;
  int rsw = (l32 & 7);   // read-side swizzle key (row%8 for both K and V reads)

  // prologue: stage tile 0 -> K[0]/V[0], tile 1 -> K[1]/V[1].
  gl_lds16(kSrcA, KSM(0) + ldsA);
  gl_lds16(kSrcB, KSM(0) + ldsB);
  gl_lds16(vSrcA, VSM(0) + ldsA);
  gl_lds16(vSrcB, VSM(0) + ldsB);
  gl_lds16(kSrcA + 64 * HEADDIM, KSM(1) + ldsA);
  gl_lds16(kSrcB + 64 * HEADDIM, KSM(1) + ldsB);
  gl_lds16(vSrcA + 64, VSM(1) + ldsA);
  gl_lds16(vSrcB + 64, VSM(1) + ldsB);
  asm volatile("s_waitcnt vmcnt(4)" ::: "memory");   // tile0 landed
  __builtin_amdgcn_s_barrier();
  __builtin_amdgcn_sched_barrier(0);

  // t = 0 (peeled): DMA tile 2, QK(0) -> sA. No softmax/PV yet.
  {
    gl_lds16(kSrcA + 2 * 64 * HEADDIM, KSM(2) + ldsA);
    gl_lds16(kSrcB + 2 * 64 * HEADDIM, KSM(2) + ldsB);
    gl_lds16(vSrcA + 2 * 64, VSM(2) + ldsA);
    gl_lds16(vSrcB + 2 * 64, VSM(2) + ldsB);
    sA0 = (f32x16){}; sA1 = (f32x16){};
    __builtin_amdgcn_s_setprio(1);
#pragma unroll
    for (int f = 0; f < 4; f++) {
      bf16x8 kfr = *(const bf16x8*)&KSM(0)[(wk32 + l32) * 64 + (((2 * f + hi) ^ rsw) * 8)];
      sA0 = MFMA(kfr, qf0[f], sA0);
      sA1 = MFMA(kfr, qf1[f], sA1);
    }
    __builtin_amdgcn_s_setprio(0);
    asm volatile("s_waitcnt vmcnt(4)" ::: "memory");   // tile1 landed; tile2 in flight
    __builtin_amdgcn_s_barrier();
    __builtin_amdgcn_sched_barrier(0);
  }

  // steady state. At entry of body t: kr=t%3, kd=(t+2)%3, vr=(t-1)%4, vd=(t+2)%4.
  int kr = 1, kd = 0, vr = 0, vd = 3;
  for (int t = 1; t < 29; t += 2) {
    ATTN_BODY(t,     sB0, sB1, sA0, sA1, true, 4);
    ATTN_BODY(t + 1, sA0, sA1, sB0, sB1, true, 4);
  }
  ATTN_BODY(29, sB0, sB1, sA0, sA1, true, 4);
  ATTN_BODY(30, sA0, sA1, sB0, sB1, false, 0);   // last landing: tile31 must arrive

  // t = 31 tail: QK(31) -> sB from K[1], softmax+PV(30) from V[2].
  {
    sB0 = (f32x16){}; sB1 = (f32x16){};
    __builtin_amdgcn_s_setprio(1);
#pragma unroll
    for (int f = 0; f < 4; f++) {
      bf16x8 kfr = *(const bf16x8*)&KSM(kr)[(wk32 + l32) * 64 + (((2 * f + hi) ^ rsw) * 8)];
      sB0 = MFMA(kfr, qf0[f], sB0);
      sB1 = MFMA(kfr, qf1[f], sB1);
    }
    __builtin_amdgcn_s_setprio(0);
    PV_STEP(vr, sA0, sA1)
    vr = (vr + 1) & 3;   // -> 3 for PV(31)
  }
  // PV of tile 31 (scores in sB, V(31) in VSM(3))
  {
    PV_STEP(vr, sB0, sB1)
  }

  // ---- cross-wave (wk) partial reduction: waves wk=1 pass Oa/Os to wk=0 ----
  __builtin_amdgcn_s_barrier();   // all waves done reading K/V LDS
  float* red = (float*)arena;
  int rbase = wq * 6144;          // 6 tiles * 4 chunks * 256 floats per wq-pair
#define WR4(T, VEC, C)                                                         \
  *(f32x4*)&red[rbase + ((T) * 4 + (C)) * 256 + lane * 4] =                    \
      (f32x4){(VEC)[(C)*4+0], (VEC)[(C)*4+1], (VEC)[(C)*4+2], (VEC)[(C)*4+3]};
#define WR16(T, VEC) WR4(T, VEC, 0) WR4(T, VEC, 1) WR4(T, VEC, 2) WR4(T, VEC, 3)
#define RD4(T, VEC, C) {                                                       \
  f32x4 t_ = *(const f32x4*)&red[rbase + ((T) * 4 + (C)) * 256 + lane * 4];    \
  (VEC)[(C)*4+0] += t_[0]; (VEC)[(C)*4+1] += t_[1];                            \
  (VEC)[(C)*4+2] += t_[2]; (VEC)[(C)*4+3] += t_[3]; }
#define RD16(T, VEC) RD4(T, VEC, 0) RD4(T, VEC, 1) RD4(T, VEC, 2) RD4(T, VEC, 3)
  if (wk == 1) {
    WR16(0, Oa00) WR16(1, Oa01) WR16(2, Oa10) WR16(3, Oa11)
    WR16(4, Os0)  WR16(5, Os1)
  }
  asm volatile("s_waitcnt lgkmcnt(0)" ::: "memory");
  __builtin_amdgcn_s_barrier();
  if (wk == 0) {
    RD16(0, Oa00) RD16(1, Oa01) RD16(2, Oa10) RD16(3, Oa11)
    RD16(4, Os0)  RD16(5, Os1)
    // store: q = q0 + wq*64 + qg*32 + (r&3)+8*(r>>2)+4*hi ; d = dg*32 + l32
    int bidx = bh >> 4, h = bh & 15;
#pragma unroll
    for (int r = 0; r < 16; r++) {
      int crow = (r & 3) + 8 * (r >> 2) + 4 * hi;
      {
        float inv = 1.0f / Os0[r];
        int sidx = q0 + wq * 64 + crow;
        size_t b2 = ((size_t)(bidx * SEQ) + sidx) * HID + h * HEADDIM;
        ctx[b2 + l32]      = f2bf(Oa00[r] * inv);
        ctx[b2 + 32 + l32] = f2bf(Oa01[r] * inv);
      }
      {
        float inv = 1.0f / Os1[r];
        int sidx = q0 + wq * 64 + 32 + crow;
        size_t b2 = ((size_t)(bidx * SEQ) + sidx) * HID + h * HEADDIM;
        ctx[b2 + l32]      = f2bf(Oa10[r] * inv);
        ctx[b2 + 32 + l32] = f2bf(Oa11[r] * inv);
      }
    }
  }
#undef KSM
#undef VSM
#undef WR4
#undef WR16
#undef RD4
#undef RD16
}

// ---------------- output projection + bias + residual ----------------
__global__ __launch_bounds__(256) void k_oproj(const ushort* __restrict__ ctx,
                                               const ushort* __restrict__ wmat,
                                               const float* __restrict__ bo,
                                               const float* __restrict__ x,
                                               float* __restrict__ out) {
  __shared__ ushort As[128 * 32];
  __shared__ ushort Bs[128 * 32];
  int tid = threadIdx.x;
  int lane = tid & 63;
  int wv = tid >> 6;
  int quad = lane >> 4;
  int l16 = lane & 15;
  int m0 = blockIdx.x * 128;
  int n0 = blockIdx.y * 128;
  const ushort* wptr = wmat + (size_t)3 * (HID * HID) + (size_t)n0 * HID;  // Wo
  int arow = tid >> 2;
  int acol = (tid & 3) * 8;
  int wm = (wv >> 1) * 64, wn = (wv & 1) * 64;

  f32x4 acc[4][4] = {};
  for (int k0 = 0; k0 < HID; k0 += 32) {
    __syncthreads();
    for (int t = 0; t < 2; t++) {
      gl_lds16(ctx + (size_t)(m0 + t * 64 + arow) * HID + k0 + acol,
               As + t * 2048 + wv * 512);
      gl_lds16(wptr + (size_t)(t * 64 + arow) * HID + k0 + acol,
               Bs + t * 2048 + wv * 512);
    }
    __syncthreads();
    bf16x8 af[4], bfr[4];
    for (int i = 0; i < 4; i++)
      af[i] = *(const bf16x8*)&As[(wm + i * 16 + l16) * 32 + quad * 8];
    for (int n = 0; n < 4; n++)
      bfr[n] = *(const bf16x8*)&Bs[(wn + n * 16 + l16) * 32 + quad * 8];
    for (int i = 0; i < 4; i++)
      for (int n = 0; n < 4; n++)
        acc[i][n] = __builtin_amdgcn_mfma_f32_16x16x32_bf16(af[i], bfr[n], acc[i][n], 0, 0, 0);
  }
  float bv4[4];
  for (int n = 0; n < 4; n++) bv4[n] = bo[n0 + wn + n * 16 + l16];
  for (int i = 0; i < 4; i++) {
    int mrow = m0 + wm + i * 16 + quad * 4;
    for (int n = 0; n < 4; n++) {
      int col = n0 + wn + n * 16 + l16;
      for (int r = 0; r < 4; r++) {
        size_t idx = (size_t)(mrow + r) * HID + col;
        out[idx] = acc[i][n][r] + bv4[n] + x[idx];
      }
    }
  }
}

extern "C" void kernel_launch(void* const* d_in, const int* in_sizes, int n_in,
                              void* d_out, int out_size, void* d_ws, size_t ws_size,
                              hipStream_t stream) {
  const float* x    = (const float*)d_in[0];
  const float* Wq   = (const float*)d_in[1];
  const float* bq   = (const float*)d_in[2];
  const float* Wk   = (const float*)d_in[3];
  const float* bk   = (const float*)d_in[4];
  const float* Wv   = (const float*)d_in[5];
  const float* bv   = (const float*)d_in[6];
  const float* Wo   = (const float*)d_in[7];
  const float* bo   = (const float*)d_in[8];
  const float* ln_g = (const float*)d_in[9];
  const float* ln_b = (const float*)d_in[10];
  float* out = (float*)d_out;

  const size_t MB = 1024 * 1024;
  ushort* ws_w = (ushort*)d_ws;                         // weights bf16, 8 MB
  ushort* xn   = (ushort*)((char*)d_ws + 8 * MB);
  ushort* Qw   = (ushort*)((char*)d_ws + 16 * MB);
  ushort* Kw   = (ushort*)((char*)d_ws + 24 * MB);
  ushort* Vw   = (ushort*)((char*)d_ws + 32 * MB);      // transposed [bh][d][s]
  ushort* Cw   = (ushort*)((char*)d_ws + 40 * MB);

  k_cvt<<<dim3(1024, 4), 256, 0, stream>>>(Wq, Wk, Wv, Wo, ws_w);
  k_ln<<<dim3(MROWS), 256, 0, stream>>>(x, ln_g, ln_b, xn);
  k_qkv<<<dim3(32, 24), 256, 0, stream>>>(xn, ws_w, bq, bk, bv, Qw, Kw, Vw);
  k_attn<<<dim3(BATCH * NHEADS, SEQ / 128), 256, 0, stream>>>(Qw, Kw, Vw, Cw);
  k_oproj<<<dim3(32, 8), 256, 0, stream>>>(Cw, ws_w, bo, x, out);
}